// Round 6
// baseline (101.675 us; speedup 1.0000x reference)
//
#include <hip/hip_runtime.h>

// Problem constants (match reference)
#define NB 8
#define HH 352
#define WW 352
#define TX 32
#define TY 16
#define TILES_X 11
#define TILES_Y 22
#define NBLK (TILES_X * TILES_Y * NB)  // 1936

#define SROW (TY + 5)    // 21  staged rows (one-sided halo: forward dy 0..5)
#define SCOL (TX + 10)   // 42  staged cols (dx -5..+5)
#define TSTR 43          // padded stride (float4 / float)
#define XROW (TY + 9)    // 25  lbl rows for mask (+/-2 beyond staged)
#define XCOL (TX + 14)   // 46  lbl cols
#define XSTR 47

// Pre-scale rgb by sqrt(ALPHA * log2(e)) so wgt = exp2(-sum(d^2)):
#define RGB_SCALE 16.98644781888824f

typedef float f32x2 __attribute__((ext_vector_type(2)));

// Pair tap: one window element q vs packed center pair; mask-weighted
// symmetric contribution (m_p + m_q) * w * |ds|.
__device__ __forceinline__ void tap_pair(const float4& wn, float mq,
                                         f32x2 cx, f32x2 cy, f32x2 cz, f32x2 cw,
                                         f32x2 mp, float& accA, float& accB) {
    f32x2 d0 = cx - wn.x;
    f32x2 d1 = cy - wn.y;
    f32x2 d2 = cz - wn.z;
    f32x2 s  = d0 * d0;
    s += d1 * d1;
    s += d2 * d2;
    f32x2 ds = cw - wn.w;
    f32x2 msum = mp + mq;
    accA = fmaf(__builtin_amdgcn_exp2f(-s.x) * msum.x, fabsf(ds.x), accA);
    accB = fmaf(__builtin_amdgcn_exp2f(-s.y) * msum.y, fabsf(ds.y), accB);
}

__device__ __forceinline__ void tap_s(const float4& wn, float mq,
                                      const float4& c, float mc, float& acc) {
    float d0 = wn.x - c.x, d1 = wn.y - c.y, d2 = wn.z - c.z;
    float s = fmaf(d0, d0, fmaf(d1, d1, d2 * d2));
    acc = fmaf(__builtin_amdgcn_exp2f(-s) * (mc + mq), fabsf(wn.w - c.w), acc);
}

__global__ __launch_bounds__(256, 6)
void btm_loss_kernel(const float* __restrict__ pred,
                     const float* __restrict__ feat,
                     float2* __restrict__ partials) {
    __shared__ float4 tile[SROW * TSTR];   // rgb(scaled)+sal, 14.4 KB
    __shared__ float  salx[XROW * XSTR];   // lbl, 4.7 KB
    __shared__ float  cpack[SROW * XSTR];  // cmin + 2*cmax (column pass), 3.9 KB
    __shared__ float  maskt[SROW * TSTR];  // final mask, 3.6 KB
    __shared__ float2 wred[4];

    int bid = blockIdx.x;
    int tx_blk = bid % TILES_X;
    int ty_blk = (bid / TILES_X) % TILES_Y;
    int n = bid / (TILES_X * TILES_Y);

    const int x0 = tx_blk * TX;
    const int y0 = ty_blk * TY;
    const int t  = threadIdx.x;

    const size_t plane = (size_t)HH * WW;
    const float* fr = feat + ((size_t)n * 3 + 0) * plane;
    const float* fg = feat + ((size_t)n * 3 + 1) * plane;
    const float* fb = feat + ((size_t)n * 3 + 2) * plane;
    const float* ps = pred + (size_t)n * plane;

    // ---- stage lbl (rows y0-2..y0+22, cols x0-7..x0+38; OOB -> 0) ----
    for (int i = t; i < XROW * XCOL; i += 256) {
        int r = i / XCOL, c = i - r * XCOL;
        int gy = y0 + r - 2, gx = x0 + c - 7;
        float l = 0.f;
        if ((unsigned)gy < (unsigned)HH && (unsigned)gx < (unsigned)WW)
            l = (ps[gy * WW + gx] > 0.5f) ? 1.f : 0.f;
        salx[r * XSTR + c] = l;
    }
    // ---- stage tile (rows y0..y0+20, cols x0-5..x0+36; OOB -> 0) ----
    for (int i = t; i < SROW * SCOL; i += 256) {
        int r = i / SCOL, c = i - r * SCOL;
        int gy = y0 + r, gx = x0 + c - 5;
        float4 v = make_float4(0.f, 0.f, 0.f, 0.f);
        if ((unsigned)gy < (unsigned)HH && (unsigned)gx < (unsigned)WW) {
            int gi = gy * WW + gx;
            v.x = fr[gi] * RGB_SCALE;
            v.y = fg[gi] * RGB_SCALE;
            v.z = fb[gi] * RGB_SCALE;
            v.w = ps[gi];
        }
        tile[r * TSTR + c] = v;
    }
    __syncthreads();

    // ---- mask pass A: column min/max of lbl over 5 rows, packed cmin+2*cmax.
    // Row-OOB feeds 1 to min (excluded), 0 to max (staged zero, neutral).
    for (int i = t; i < SROW * XCOL; i += 256) {
        int r = i / XCOL, c = i - r * XCOL;
        bool colv = (unsigned)(x0 + c - 7) < (unsigned)WW;
        float mn = 1.f, mx = 0.f;
        #pragma unroll
        for (int rr = 0; rr < 5; ++rr) {
            float v = salx[(r + rr) * XSTR + c];
            bool rowv = (unsigned)(y0 + r - 2 + rr) < (unsigned)HH;
            mx = fmaxf(mx, v);
            mn = fminf(mn, (rowv && colv) ? v : 1.f);
        }
        cpack[r * XSTR + c] = fmaf(2.f, mx, mn);  // {0,1,2,3}
    }
    __syncthreads();

    // ---- mask pass B: 5-wide horizontal; dil = max(v)>=1.5, ero = min(v)>=2.5
    bool pbx = (tx_blk == 0) || (tx_blk == TILES_X - 1) || (ty_blk == TILES_Y - 1);
    for (int i = t; i < SROW * SCOL; i += 256) {
        int r = i / SCOL, c = i - r * SCOL;
        float vmx = 0.f, vmn = 3.f;
        if (!pbx) {
            #pragma unroll
            for (int j = 0; j < 5; ++j) {
                float v = cpack[r * XSTR + c + j];
                vmx = fmaxf(vmx, v);
                vmn = fminf(vmn, v);
            }
            maskt[r * TSTR + c] =
                ((vmx >= 1.5f) ? 1.f : 0.f) - ((vmn >= 2.5f) ? 1.f : 0.f);
        } else {
            #pragma unroll
            for (int j = 0; j < 5; ++j) {
                float v = cpack[r * XSTR + c + j];
                bool cv = (unsigned)(x0 + c - 7 + j) < (unsigned)WW;
                vmx = fmaxf(vmx, v);
                vmn = fminf(vmn, cv ? v : 3.f);
            }
            float m = ((vmx >= 1.5f) ? 1.f : 0.f) - ((vmn >= 2.5f) ? 1.f : 0.f);
            bool posv = ((unsigned)(y0 + r) < (unsigned)HH) &&
                        ((unsigned)(x0 + c - 5) < (unsigned)WW);
            maskt[r * TSTR + c] = posv ? m : 0.f;  // pad positions: mask 0
        }
    }
    __syncthreads();

    // ---- forward-tap accumulation (60 offsets/pixel, symmetry-halved) ----
    const int g   = t >> 7;      // 0: dy 0..2, 1: dy 3..5
    const int tl  = t & 127;
    const int txq = tl & 7;
    const int ty  = tl >> 3;     // 0..15
    const int px0 = txq * 4;
    const int cb  = ty * TSTR + px0;

    float4 c0 = tile[cb + 5], c1 = tile[cb + 6], c2 = tile[cb + 7], c3 = tile[cb + 8];
    float  m0 = maskt[cb + 5], m1 = maskt[cb + 6], m2 = maskt[cb + 7], m3 = maskt[cb + 8];

    f32x2 c01x = {c0.x, c1.x}, c01y = {c0.y, c1.y}, c01z = {c0.z, c1.z}, c01w = {c0.w, c1.w};
    f32x2 c23x = {c2.x, c3.x}, c23y = {c2.y, c3.y}, c23z = {c2.z, c3.z}, c23w = {c2.w, c3.w};
    f32x2 mp01 = {m0, m1}, mp23 = {m2, m3};

    float acc0 = 0.f, acc1 = 0.f, acc2 = 0.f, acc3 = 0.f;

    const int dy_lo = g ? 3 : 1;
    const int dy_hi = g ? 6 : 3;
    for (int dy = dy_lo; dy < dy_hi; ++dy) {
        const float4* row  = &tile[(ty + dy) * TSTR + px0];
        const float*  mrow = &maskt[(ty + dy) * TSTR + px0];
        float4 wv[14]; float mv[14];
        #pragma unroll
        for (int j = 0; j < 14; ++j) { wv[j] = row[j]; mv[j] = mrow[j]; }

        tap_s(wv[0],  mv[0],  c0, m0, acc0);
        tap_s(wv[11], mv[11], c1, m1, acc1);
        tap_s(wv[2],  mv[2],  c2, m2, acc2);
        tap_s(wv[13], mv[13], c3, m3, acc3);
        #pragma unroll
        for (int j = 1; j <= 10; ++j)
            tap_pair(wv[j], mv[j], c01x, c01y, c01z, c01w, mp01, acc0, acc1);
        #pragma unroll
        for (int j = 3; j <= 12; ++j)
            tap_pair(wv[j], mv[j], c23x, c23y, c23z, c23w, mp23, acc2, acc3);
    }
    if (g == 0) {  // dy = 0 partial row: forward dx 1..5 only (tile cols +6..+13)
        const float4* row  = &tile[ty * TSTR + px0];
        const float*  mrow = &maskt[ty * TSTR + px0];
        float4 wv[8]; float mv[8];
        #pragma unroll
        for (int j = 0; j < 8; ++j) { wv[j] = row[6 + j]; mv[j] = mrow[6 + j]; }

        tap_s(wv[0], mv[0], c0, m0, acc0);   // c0 @ dx=1
        tap_s(wv[5], mv[5], c1, m1, acc1);   // c1 @ dx=5
        tap_s(wv[2], mv[2], c2, m2, acc2);   // c2 @ dx=1
        tap_s(wv[7], mv[7], c3, m3, acc3);   // c3 @ dx=5
        #pragma unroll
        for (int j = 1; j <= 4; ++j)
            tap_pair(wv[j], mv[j], c01x, c01y, c01z, c01w, mp01, acc0, acc1);
        #pragma unroll
        for (int j = 3; j <= 6; ++j)
            tap_pair(wv[j], mv[j], c23x, c23y, c23z, c23w, mp23, acc2, acc3);
    }

    float num = (acc0 + acc1) + (acc2 + acc3);
    float den = 0.f;
    if (g == 0) {
        den = (m0 + m1) + (m2 + m3);
        // Closed-form backward-pad term: every OOB backward neighbor of p
        // contributes exp2(-|rgb_p|^2) * sal_p. Count n_boob from coords.
        bool padblk = (tx_blk == 0) || (tx_blk == TILES_X - 1) || (ty_blk == 0);
        if (padblk) {
            int y = y0 + ty;
            int ry = max(0, 5 - y);
            const float4 cc[4] = {c0, c1, c2, c3};
            const float  mm[4] = {m0, m1, m2, m3};
            float accP = 0.f;
            #pragma unroll
            for (int k = 0; k < 4; ++k) {
                int x = x0 + px0 + k;
                int lx = max(0, 5 - x);
                int rx = max(0, x - 346);
                int nb = ry * 11 + (5 - ry) * (lx + rx) + lx;
                float s = fmaf(cc[k].x, cc[k].x,
                          fmaf(cc[k].y, cc[k].y, cc[k].z * cc[k].z));
                accP = fmaf(mm[k] * (float)nb,
                            __builtin_amdgcn_exp2f(-s) * cc[k].w, accP);
            }
            num += accP;
        }
    }

    // ---- wave reduce -> block reduce -> deterministic partial store ----
    #pragma unroll
    for (int off = 32; off > 0; off >>= 1) {
        num += __shfl_down(num, off, 64);
        den += __shfl_down(den, off, 64);
    }
    int wid  = t >> 6;
    int lane = t & 63;
    if (lane == 0) wred[wid] = make_float2(num, den);
    __syncthreads();
    if (t == 0) {
        float2 a = wred[0];
        #pragma unroll
        for (int w = 1; w < 4; ++w) { a.x += wred[w].x; a.y += wred[w].y; }
        partials[bid] = a;
    }
}

__global__ __launch_bounds__(256)
void btm_finalize_kernel(const float2* __restrict__ partials,
                         float* __restrict__ out) {
    __shared__ float2 wred[4];
    float num = 0.f, den = 0.f;
    for (int i = threadIdx.x; i < NBLK; i += 256) {
        float2 p = partials[i];
        num += p.x;
        den += p.y;
    }
    #pragma unroll
    for (int off = 32; off > 0; off >>= 1) {
        num += __shfl_down(num, off, 64);
        den += __shfl_down(den, off, 64);
    }
    int wid  = threadIdx.x >> 6;
    int lane = threadIdx.x & 63;
    if (lane == 0) wred[wid] = make_float2(num, den);
    __syncthreads();
    if (threadIdx.x == 0) {
        float2 a = wred[0];
        #pragma unroll
        for (int w = 1; w < 4; ++w) { a.x += wred[w].x; a.y += wred[w].y; }
        out[0] = a.x / (a.y + 1e-6f);
    }
}

extern "C" void kernel_launch(void* const* d_in, const int* in_sizes, int n_in,
                              void* d_out, int out_size, void* d_ws, size_t ws_size,
                              hipStream_t stream) {
    const float* pred = (const float*)d_in[0];  // (8,1,352,352) fp32
    const float* feat = (const float*)d_in[1];  // (8,3,352,352) fp32
    float* out = (float*)d_out;                 // scalar fp32
    float2* partials = (float2*)d_ws;           // NBLK float2 = 15.5 KB

    btm_loss_kernel<<<dim3(NBLK), dim3(256), 0, stream>>>(pred, feat, partials);
    btm_finalize_kernel<<<dim3(1), dim3(256), 0, stream>>>(partials, out);
}